// Round 3
// baseline (26103.726 us; speedup 1.0000x reference)
//
#include <hip/hip_runtime.h>

typedef _Float16 f16;
typedef f16 h8 __attribute__((ext_vector_type(8)));
typedef f16 h4 __attribute__((ext_vector_type(4)));
typedef float f4 __attribute__((ext_vector_type(4)));

#define ROWS 64
#define HH 256
#define TT 200
#define NTHR 512
#define NWG 128
#define OSTR 129

static __device__ __forceinline__ f4 mfma16(h8 a, h8 b, f4 c) {
  return __builtin_amdgcn_mfma_f32_16x16x32_f16(a, b, c, 0, 0, 0);
}
static __device__ __forceinline__ f4 fzero() { f4 z; z[0]=0.f; z[1]=0.f; z[2]=0.f; z[3]=0.f; return z; }
static __device__ __forceinline__ float sigm(float x) { return 1.0f / (1.0f + __expf(-x)); }
static __device__ __forceinline__ float tanhfast(float x) {
  float t = __expf(-2.0f * fabsf(x));
  float r = (1.0f - t) / (1.0f + t);
  return copysignf(r, x);
}
// swizzled f16 [64][256] LDS tile: 16B chunks XORed by row&7 -> conflict-free ds_read_b128
static __device__ __forceinline__ void hstore(f16* hs, int r, int d, f16 v) {
  hs[r * HH + ((((d >> 3) ^ (r & 7)) << 3) | (d & 7))] = v;
}
static __device__ __forceinline__ h8 hload8(const f16* hs, int r, int kc) {
  return ((const h8*)hs)[r * 32 + (kc ^ (r & 7))];
}

// Pre-convert + fragment-order swizzle the 4 streamed weight matrices to f16 in ws.
// Layout per matrix: [n_tile][k_chunk(32)][row_in_tile(16)] of h8.
__global__ void conv_w(const float* __restrict__ whh0, const float* __restrict__ wih1,
                       const float* __restrict__ whh1, const float* __restrict__ ow1,
                       f16* __restrict__ dst) {
  int i = blockIdx.x * 256 + threadIdx.x;  // 0 .. 819199
  const float* src;
  int base;
  if (i < 262144)      { src = whh0; base = 0; }
  else if (i < 524288) { src = wih1; base = 262144; }
  else if (i < 786432) { src = whh1; base = 524288; }
  else                 { src = ow1;  base = 786432; }
  int e = i - base;
  int row = e >> 8, col = e & 255;
  int idx = base + ((((row >> 4) << 5) + (col >> 3)) << 7) + ((row & 15) << 3) + (col & 7);
  dst[idx] = (f16)src[e];
}

// Half-gate GEMM: 4 n-tiles (wv + 8*(JB+j), j=0..3) x 4 m-tiles, K=256.
// B-fragments double-buffered across k (prefetch k+1 while MFMA k).
#define GEMM_HALF(ACC, HS, WMAT, JB)                                                     \
  {                                                                                      \
    h8 bb[2][4];                                                                         \
    _Pragma("unroll")                                                                    \
    for (int j = 0; j < 4; ++j)                                                          \
      bb[0][j] = (WMAT)[((wv + 8 * ((JB) + j)) << 9) + (lg << 4) + lr];                  \
    _Pragma("unroll")                                                                    \
    for (int k = 0; k < 8; ++k) {                                                        \
      if (k < 7) {                                                                       \
        _Pragma("unroll")                                                                \
        for (int j = 0; j < 4; ++j)                                                      \
          bb[(k + 1) & 1][j] =                                                           \
              (WMAT)[((wv + 8 * ((JB) + j)) << 9) + ((((k + 1) << 2) + lg) << 4) + lr];  \
      }                                                                                  \
      h8 aa[4];                                                                          \
      _Pragma("unroll")                                                                  \
      for (int m = 0; m < 4; ++m) aa[m] = hload8(HS, (m << 4) + lr, (k << 2) + lg);      \
      _Pragma("unroll")                                                                  \
      for (int j = 0; j < 4; ++j) {                                                      \
        _Pragma("unroll")                                                                \
        for (int m = 0; m < 4; ++m)                                                      \
          ACC[j][m] = mfma16(aa[m], bb[k & 1][j], ACC[j][m]);                            \
      }                                                                                  \
    }                                                                                    \
  }

__global__ __attribute__((amdgpu_flat_work_group_size(NTHR, NTHR), amdgpu_waves_per_eu(2, 2)))
void traj_kernel(const float* __restrict__ x,
                 const float* __restrict__ ew1, const float* __restrict__ eb1,
                 const float* __restrict__ ew2, const float* __restrict__ eb2,
                 const float* __restrict__ ew3, const float* __restrict__ eb3,
                 const float* __restrict__ hiw, const float* __restrict__ hib,
                 const float* __restrict__ ciw, const float* __restrict__ cib,
                 const float* __restrict__ wih0,
                 const float* __restrict__ bih0, const float* __restrict__ bhh0,
                 const float* __restrict__ bih1, const float* __restrict__ bhh1,
                 const float* __restrict__ ob1, const float* __restrict__ ow2,
                 const float* __restrict__ ob2, const float* __restrict__ stok,
                 const f16* __restrict__ wk, float* __restrict__ out)
{
  __shared__ __align__(16) f16 h0s[ROWS * HH];   // 32 KB (swizzled h0 / plain e buffer)
  __shared__ __align__(16) f16 h1s[ROWS * HH];   // 32 KB
  __shared__ float o1s[ROWS * OSTR];             // 33 KB
  __shared__ f16 wih0s[1024 * 3];                // 6 KB
  __shared__ f16 b0s[1024];                      // 2 KB (b_ih0 + b_hh0)
  __shared__ f16 b1s[1024];                      // 2 KB
  __shared__ float w2s[3 * 128];                 // 1.5 KB
  __shared__ float ob1s[128];
  __shared__ float decs[ROWS * 3];
  __shared__ float ob2s[4];

  const int tid  = threadIdx.x;
  const int wv   = tid >> 6;
  const int lane = tid & 63;
  const int lr   = lane & 15;
  const int lg   = lane >> 4;
  const int row0 = blockIdx.x * ROWS;

  const h8* W0  = (const h8*)wk;                 // w_hh0  [1024][256] frag-order
  const h8* W1i = (const h8*)(wk + 262144);      // w_ih1
  const h8* W1h = (const h8*)(wk + 524288);      // w_hh1
  const h8* OW1 = (const h8*)(wk + 786432);      // out_w1 [128][256]

  // ---- stage small constants ----
  for (int i = tid; i < 3072; i += NTHR) wih0s[i] = (f16)wih0[i];
  for (int i = tid; i < 1024; i += NTHR) {
    b0s[i] = (f16)(bih0[i] + bhh0[i]);
    b1s[i] = (f16)(bih1[i] + bhh1[i]);
  }
  for (int i = tid; i < 384; i += NTHR) w2s[i] = ow2[i];
  if (tid < 128) ob1s[tid] = ob1[tid];
  if (tid < 192) decs[tid] = stok[tid % 3];
  if (tid < 3)   ob2s[tid] = ob2[tid];
  __syncthreads();

  // ---------------- encoder (one-time, fp32 VALU; e buffers plain f16) ----------------
  {
    const int r  = tid >> 3;           // 64 rows, 8 threads each
    const int cb = (tid & 7) << 5;     // 32 cols per thread
    float xr[7];
    #pragma unroll
    for (int k = 0; k < 7; ++k) xr[k] = x[(row0 + r) * 7 + k];
    for (int c32 = 0; c32 < 32; ++c32) {           // e1 -> h1s (plain)
      int c = cb + c32;
      float a = eb1[c];
      #pragma unroll
      for (int k = 0; k < 7; ++k) a += xr[k] * ew1[c * 7 + k];
      h1s[r * HH + c] = (f16)fmaxf(a, 0.0f);
    }
    __syncthreads();
    const f4* W2v = (const f4*)ew2;
    for (int cc = 0; cc < 8; ++cc) {               // e2 -> h0s
      int c0 = cb + (cc << 2);
      float a0 = eb2[c0], a1 = eb2[c0+1], a2 = eb2[c0+2], a3 = eb2[c0+3];
      for (int k4 = 0; k4 < 64; ++k4) {
        h4 ev = ((const h4*)h1s)[(r << 6) + k4];
        f4 w0 = W2v[(c0+0)*64 + k4], w1 = W2v[(c0+1)*64 + k4],
           w2 = W2v[(c0+2)*64 + k4], w3 = W2v[(c0+3)*64 + k4];
        #pragma unroll
        for (int j = 0; j < 4; ++j) {
          float e = (float)ev[j];
          a0 += e * w0[j]; a1 += e * w1[j]; a2 += e * w2[j]; a3 += e * w3[j];
        }
      }
      h0s[r * HH + c0 + 0] = (f16)fmaxf(a0, 0.0f);
      h0s[r * HH + c0 + 1] = (f16)fmaxf(a1, 0.0f);
      h0s[r * HH + c0 + 2] = (f16)fmaxf(a2, 0.0f);
      h0s[r * HH + c0 + 3] = (f16)fmaxf(a3, 0.0f);
    }
    __syncthreads();
    const f4* W3v = (const f4*)ew3;
    for (int cc = 0; cc < 8; ++cc) {               // e3 -> h1s
      int c0 = cb + (cc << 2);
      float a0 = eb3[c0], a1 = eb3[c0+1], a2 = eb3[c0+2], a3 = eb3[c0+3];
      for (int k4 = 0; k4 < 64; ++k4) {
        h4 ev = ((const h4*)h0s)[(r << 6) + k4];
        f4 w0 = W3v[(c0+0)*64 + k4], w1 = W3v[(c0+1)*64 + k4],
           w2 = W3v[(c0+2)*64 + k4], w3 = W3v[(c0+3)*64 + k4];
        #pragma unroll
        for (int j = 0; j < 4; ++j) {
          float e = (float)ev[j];
          a0 += e * w0[j]; a1 += e * w1[j]; a2 += e * w2[j]; a3 += e * w3[j];
        }
      }
      h1s[r * HH + c0 + 0] = (f16)fmaxf(a0, 0.0f);
      h1s[r * HH + c0 + 1] = (f16)fmaxf(a1, 0.0f);
      h1s[r * HH + c0 + 2] = (f16)fmaxf(a2, 0.0f);
      h1s[r * HH + c0 + 3] = (f16)fmaxf(a3, 0.0f);
    }
    __syncthreads();
  }

  // ---------------- h/c init from e3 (plain in h1s) ----------------
  float c0v[2][4][4], c1v[2][4][4];
  h4 qv[2][4];                        // sigm(i) carried between halves, f16
  float h1st[2][16];
  {
    const f4* HIW4 = (const f4*)hiw;
    const f4* CIW4 = (const f4*)ciw;
    #pragma unroll
    for (int hi = 0; hi < 2; ++hi) {
      const int d = ((wv + 8 * hi) << 4) + lr;
      float aH0[16], aC0[16], aH1[16], aC1[16];
      #pragma unroll
      for (int ri = 0; ri < 16; ++ri) { aH0[ri]=0.f; aC0[ri]=0.f; aH1[ri]=0.f; aC1[ri]=0.f; }
      for (int k4 = 0; k4 < 64; ++k4) {
        f4 wh0 = HIW4[d * 64 + k4];
        f4 wc0 = CIW4[d * 64 + k4];
        f4 wh1 = HIW4[(256 + d) * 64 + k4];
        f4 wc1 = CIW4[(256 + d) * 64 + k4];
        #pragma unroll
        for (int ri = 0; ri < 16; ++ri) {
          const int r = ((ri >> 2) << 4) + (lg << 2) + (ri & 3);
          h4 ev4 = ((const h4*)h1s)[(r << 6) + k4];
          #pragma unroll
          for (int j = 0; j < 4; ++j) {
            float e = (float)ev4[j];
            aH0[ri] += e * wh0[j];
            aC0[ri] += e * wc0[j];
            aH1[ri] += e * wh1[j];
            aC1[ri] += e * wc1[j];
          }
        }
      }
      const float bh0 = hib[d], bc0 = cib[d], bh1v = hib[256 + d], bc1 = cib[256 + d];
      #pragma unroll
      for (int ri = 0; ri < 16; ++ri) {
        c0v[hi][ri >> 2][ri & 3] = aC0[ri] + bc0;
        c1v[hi][ri >> 2][ri & 3] = aC1[ri] + bc1;
        h1st[hi][ri] = aH1[ri] + bh1v;
        const int r = ((ri >> 2) << 4) + (lg << 2) + (ri & 3);
        hstore(h0s, r, d, (f16)(aH0[ri] + bh0));   // h0s held dead e2
      }
    }
  }
  __syncthreads();  // all e3 reads of h1s done
  #pragma unroll
  for (int hi = 0; hi < 2; ++hi) {
    const int d = ((wv + 8 * hi) << 4) + lr;
    #pragma unroll
    for (int ri = 0; ri < 16; ++ri) {
      const int r = ((ri >> 2) << 4) + (lg << 2) + (ri & 3);
      hstore(h1s, r, d, (f16)h1st[hi][ri]);
    }
  }
  __syncthreads();

  // ---------------- T = 200 sequential decoder steps ----------------
  for (int t = 0; t < TT; ++t) {
    // ======== layer 0, half A: gates i,f ========
    f4 acc[4][4];
    #pragma unroll
    for (int j = 0; j < 4; ++j)
      #pragma unroll
      for (int m = 0; m < 4; ++m) acc[j][m] = fzero();
    GEMM_HALF(acc, h0s, W0, 0);
    #pragma unroll
    for (int hi = 0; hi < 2; ++hi) {
      const int col = ((wv + 8 * hi) << 4) + lr;
      const float wI0 = (float)wih0s[col*3], wI1 = (float)wih0s[col*3+1], wI2 = (float)wih0s[col*3+2];
      const float wF0 = (float)wih0s[(256+col)*3], wF1 = (float)wih0s[(256+col)*3+1], wF2 = (float)wih0s[(256+col)*3+2];
      const float bI = (float)b0s[col], bF = (float)b0s[256 + col];
      #pragma unroll
      for (int m = 0; m < 4; ++m)
        #pragma unroll
        for (int i = 0; i < 4; ++i) {
          const int r = (m << 4) + (lg << 2) + i;
          const float d0 = decs[r*3], d1 = decs[r*3+1], d2 = decs[r*3+2];
          float gI = acc[hi][m][i]     + bI + d0*wI0 + d1*wI1 + d2*wI2;
          float gF = acc[2 + hi][m][i] + bF + d0*wF0 + d1*wF1 + d2*wF2;
          qv[hi][m][i] = (f16)sigm(gI);
          c0v[hi][m][i] *= sigm(gF);      // p = sigm(f)*c
        }
    }
    // ======== layer 0, half B: gates g,o ========
    #pragma unroll
    for (int j = 0; j < 4; ++j)
      #pragma unroll
      for (int m = 0; m < 4; ++m) acc[j][m] = fzero();
    GEMM_HALF(acc, h0s, W0, 4);
    __syncthreads();   // all waves' h0s reads done before writes
    #pragma unroll
    for (int hi = 0; hi < 2; ++hi) {
      const int col = ((wv + 8 * hi) << 4) + lr;
      const float wG0 = (float)wih0s[(512+col)*3], wG1 = (float)wih0s[(512+col)*3+1], wG2 = (float)wih0s[(512+col)*3+2];
      const float wO0 = (float)wih0s[(768+col)*3], wO1 = (float)wih0s[(768+col)*3+1], wO2 = (float)wih0s[(768+col)*3+2];
      const float bG = (float)b0s[512 + col], bO = (float)b0s[768 + col];
      #pragma unroll
      for (int m = 0; m < 4; ++m)
        #pragma unroll
        for (int i = 0; i < 4; ++i) {
          const int r = (m << 4) + (lg << 2) + i;
          const float d0 = decs[r*3], d1 = decs[r*3+1], d2 = decs[r*3+2];
          float gG = acc[hi][m][i]     + bG + d0*wG0 + d1*wG1 + d2*wG2;
          float gO = acc[2 + hi][m][i] + bO + d0*wO0 + d1*wO1 + d2*wO2;
          float cn = c0v[hi][m][i] + (float)qv[hi][m][i] * tanhfast(gG);
          c0v[hi][m][i] = cn;
          hstore(h0s, r, col, (f16)(sigm(gO) * tanhfast(cn)));
        }
    }
    __syncthreads();

    // ======== layer 1, half A: gates i,f ========
    #pragma unroll
    for (int j = 0; j < 4; ++j)
      #pragma unroll
      for (int m = 0; m < 4; ++m) acc[j][m] = fzero();
    GEMM_HALF(acc, h0s, W1i, 0);
    GEMM_HALF(acc, h1s, W1h, 0);
    #pragma unroll
    for (int hi = 0; hi < 2; ++hi) {
      const int col = ((wv + 8 * hi) << 4) + lr;
      const float bI = (float)b1s[col], bF = (float)b1s[256 + col];
      #pragma unroll
      for (int m = 0; m < 4; ++m)
        #pragma unroll
        for (int i = 0; i < 4; ++i) {
          float gI = acc[hi][m][i]     + bI;
          float gF = acc[2 + hi][m][i] + bF;
          qv[hi][m][i] = (f16)sigm(gI);
          c1v[hi][m][i] *= sigm(gF);
        }
    }
    // ======== layer 1, half B: gates g,o ========
    #pragma unroll
    for (int j = 0; j < 4; ++j)
      #pragma unroll
      for (int m = 0; m < 4; ++m) acc[j][m] = fzero();
    GEMM_HALF(acc, h0s, W1i, 4);
    GEMM_HALF(acc, h1s, W1h, 4);
    __syncthreads();   // all waves' h1s reads done before writes
    #pragma unroll
    for (int hi = 0; hi < 2; ++hi) {
      const int col = ((wv + 8 * hi) << 4) + lr;
      const float bG = (float)b1s[512 + col], bO = (float)b1s[768 + col];
      #pragma unroll
      for (int m = 0; m < 4; ++m)
        #pragma unroll
        for (int i = 0; i < 4; ++i) {
          const int r = (m << 4) + (lg << 2) + i;
          float gG = acc[hi][m][i]     + bG;
          float gO = acc[2 + hi][m][i] + bO;
          float cn = c1v[hi][m][i] + (float)qv[hi][m][i] * tanhfast(gG);
          c1v[hi][m][i] = cn;
          hstore(h1s, r, col, (f16)(sigm(gO) * tanhfast(cn)));
        }
    }
    __syncthreads();

    // ======== out head: o1 = relu(h1n @ out_w1^T + b1) ========
    {
      f4 oa[4];
      #pragma unroll
      for (int m = 0; m < 4; ++m) oa[m] = fzero();
      #pragma unroll
      for (int k = 0; k < 8; ++k) {
        h8 b = OW1[(wv << 9) + (((k << 2) + lg) << 4) + lr];
        #pragma unroll
        for (int m = 0; m < 4; ++m)
          oa[m] = mfma16(hload8(h1s, (m << 4) + lr, (k << 2) + lg), b, oa[m]);
      }
      const float obv = ob1s[(wv << 4) + lr];
      #pragma unroll
      for (int m = 0; m < 4; ++m)
        #pragma unroll
        for (int i = 0; i < 4; ++i) {
          const int r = (m << 4) + (lg << 2) + i;
          o1s[r * OSTR + (wv << 4) + lr] = fmaxf(oa[m][i] + obv, 0.0f);
        }
    }
    __syncthreads();

    // ======== final: out = o1 @ out_w2^T + b2 ; feed back as dec ========
    {
      const int r = tid >> 3;          // 64 rows x 8 threads
      const int j = tid & 7;           // 16-wide k chunk each
      float a0 = 0.f, a1 = 0.f, a2 = 0.f;
      #pragma unroll
      for (int kk = 0; kk < 16; ++kk) {
        const int k = (j << 4) + kk;
        const float ov = o1s[r * OSTR + k];
        a0 += ov * w2s[k];
        a1 += ov * w2s[128 + k];
        a2 += ov * w2s[256 + k];
      }
      #pragma unroll
      for (int s = 4; s >= 1; s >>= 1) {
        a0 += __shfl_xor(a0, s);
        a1 += __shfl_xor(a1, s);
        a2 += __shfl_xor(a2, s);
      }
      if (j == 0) {
        a0 += ob2s[0]; a1 += ob2s[1]; a2 += ob2s[2];
        float* op = out + ((size_t)(row0 + r) * TT + t) * 3;
        op[0] = a0; op[1] = a1; op[2] = a2;
        decs[r * 3 + 0] = a0; decs[r * 3 + 1] = a1; decs[r * 3 + 2] = a2;
      }
    }
    __syncthreads();
  }
}

extern "C" void kernel_launch(void* const* d_in, const int* in_sizes, int n_in,
                              void* d_out, int out_size, void* d_ws, size_t ws_size,
                              hipStream_t stream) {
  (void)in_sizes; (void)n_in; (void)out_size; (void)ws_size;
  f16* wk = (f16*)d_ws;
  conv_w<<<3200, 256, 0, stream>>>((const float*)d_in[12], (const float*)d_in[15],
                                   (const float*)d_in[16], (const float*)d_in[19], wk);
  traj_kernel<<<NWG, NTHR, 0, stream>>>(
      (const float*)d_in[0],
      (const float*)d_in[1],  (const float*)d_in[2],
      (const float*)d_in[3],  (const float*)d_in[4],
      (const float*)d_in[5],  (const float*)d_in[6],
      (const float*)d_in[7],  (const float*)d_in[8],
      (const float*)d_in[9],  (const float*)d_in[10],
      (const float*)d_in[11],
      (const float*)d_in[13], (const float*)d_in[14],
      (const float*)d_in[17], (const float*)d_in[18],
      (const float*)d_in[20], (const float*)d_in[21],
      (const float*)d_in[22], (const float*)d_in[23],
      wk, (float*)d_out);
}

// Round 4
// 24200.624 us; speedup vs baseline: 1.0786x; 1.0786x over previous
//
#include <hip/hip_runtime.h>

typedef _Float16 f16;
typedef f16 h8v __attribute__((ext_vector_type(8)));
typedef f16 h4v __attribute__((ext_vector_type(4)));
typedef float f4v __attribute__((ext_vector_type(4)));

#define ROWS 32
#define HH 256
#define TT 200
#define NTHR 512
#define NWG 256
#define OSTR 132

static __device__ __forceinline__ f4v mfma16(h8v a, h8v b, f4v c) {
  return __builtin_amdgcn_mfma_f32_16x16x32_f16(a, b, c, 0, 0, 0);
}
static __device__ __forceinline__ f4v fzero() { f4v z; z[0]=0.f; z[1]=0.f; z[2]=0.f; z[3]=0.f; return z; }
static __device__ __forceinline__ float sigm(float x) { return 1.0f / (1.0f + __expf(-x)); }
static __device__ __forceinline__ float tanhfast(float x) {
  float t = __expf(-2.0f * fabsf(x));
  float r = (1.0f - t) / (1.0f + t);
  return copysignf(r, x);
}
// swizzled f16 [32][256] LDS tile: 16B chunks XORed by row&7 -> conflict-free ds_read_b128
static __device__ __forceinline__ void hstore(f16* hs, int r, int d, f16 v) {
  hs[r * HH + ((((d >> 3) ^ (r & 7)) << 3) | (d & 7))] = v;
}
static __device__ __forceinline__ h8v hload8(const f16* hs, int r, int kc) {
  return ((const h8v*)hs)[r * 32 + (kc ^ (r & 7))];
}

// Pre-convert + fragment-order swizzle the 4 streamed weight matrices to f16 in ws.
// Layout per matrix: [n_tile][k_chunk(32)][row_in_tile(16)] of h8v.  (unchanged from R1-3)
__global__ void conv_w(const float* __restrict__ whh0, const float* __restrict__ wih1,
                       const float* __restrict__ whh1, const float* __restrict__ ow1,
                       f16* __restrict__ dst) {
  int i = blockIdx.x * 256 + threadIdx.x;  // 0 .. 819199
  const float* src;
  int base;
  if (i < 262144)      { src = whh0; base = 0; }
  else if (i < 524288) { src = wih1; base = 262144; }
  else if (i < 786432) { src = whh1; base = 524288; }
  else                 { src = ow1;  base = 786432; }
  int e = i - base;
  int row = e >> 8, col = e & 255;
  int idx = base + ((((row >> 4) << 5) + (col >> 3)) << 7) + ((row & 15) << 3) + (col & 7);
  dst[idx] = (f16)src[e];
}

// One K=256 GEMM pass, 2 n-tiles x 2 m-tiles, B-ring depth 3 (prefetch distance 2).
#define GEMM8(ACC, HS, WB, NT0, NT1)                                                   \
  {                                                                                    \
    h8v bb[3][2];                                                                      \
    bb[0][0] = (WB)[((NT0) << 9) + (lg << 4) + lr];                                    \
    bb[0][1] = (WB)[((NT1) << 9) + (lg << 4) + lr];                                    \
    bb[1][0] = (WB)[((NT0) << 9) + ((4 + lg) << 4) + lr];                              \
    bb[1][1] = (WB)[((NT1) << 9) + ((4 + lg) << 4) + lr];                              \
    _Pragma("unroll")                                                                  \
    for (int k = 0; k < 8; ++k) {                                                      \
      if (k < 6) {                                                                     \
        bb[(k + 2) % 3][0] = (WB)[((NT0) << 9) + ((((k + 2) << 2) + lg) << 4) + lr];   \
        bb[(k + 2) % 3][1] = (WB)[((NT1) << 9) + ((((k + 2) << 2) + lg) << 4) + lr];   \
      }                                                                                \
      h8v a0_ = hload8(HS, lr, (k << 2) + lg);                                         \
      h8v a1_ = hload8(HS, 16 + lr, (k << 2) + lg);                                    \
      ACC[0][0] = mfma16(a0_, bb[k % 3][0], ACC[0][0]);                                \
      ACC[0][1] = mfma16(a1_, bb[k % 3][0], ACC[0][1]);                                \
      ACC[1][0] = mfma16(a0_, bb[k % 3][1], ACC[1][0]);                                \
      ACC[1][1] = mfma16(a1_, bb[k % 3][1], ACC[1][1]);                                \
    }                                                                                  \
  }

__global__ __launch_bounds__(NTHR, 2)
void traj_kernel(const float* __restrict__ x,
                 const float* __restrict__ ew1, const float* __restrict__ eb1,
                 const float* __restrict__ ew2, const float* __restrict__ eb2,
                 const float* __restrict__ ew3, const float* __restrict__ eb3,
                 const float* __restrict__ hiw, const float* __restrict__ hib,
                 const float* __restrict__ ciw, const float* __restrict__ cib,
                 const float* __restrict__ wih0,
                 const float* __restrict__ bih0, const float* __restrict__ bhh0,
                 const float* __restrict__ bih1, const float* __restrict__ bhh1,
                 const float* __restrict__ ob1, const float* __restrict__ ow2,
                 const float* __restrict__ ob2, const float* __restrict__ stok,
                 const f16* __restrict__ wk, float* __restrict__ out)
{
  __shared__ __align__(16) f16 h0s[ROWS * HH];   // 16 KB swizzled h0 (or e2 staging)
  __shared__ __align__(16) f16 h1s[ROWS * HH];   // 16 KB swizzled h1 (or e1/e3 staging)
  __shared__ f16 o1s[ROWS * OSTR];               // 8.4 KB
  __shared__ f16 wih0s[1024 * 3];                // 6 KB
  __shared__ f16 b0s[1024];                      // 2 KB (b_ih0 + b_hh0)
  __shared__ f16 b1s[1024];                      // 2 KB
  __shared__ float w2s[3 * 128];                 // 1.5 KB
  __shared__ float ob1s[128];
  __shared__ float decs[ROWS * 3];
  __shared__ float ob2s[4];

  const int tid  = threadIdx.x;
  const int wv   = tid >> 6;
  const int lane = tid & 63;
  const int lr   = lane & 15;
  const int lg   = lane >> 4;
  const int row0 = blockIdx.x * ROWS;

  const h8v* W0  = (const h8v*)wk;               // w_hh0  [64 n-tiles][32 kc][16] frag-order
  const h8v* W1i = (const h8v*)(wk + 262144);    // w_ih1
  const h8v* W1h = (const h8v*)(wk + 524288);    // w_hh1
  const h8v* OW1 = (const h8v*)(wk + 786432);    // out_w1 [8 n-tiles][32 kc][16]

  // ---- stage small constants ----
  for (int i = tid; i < 3072; i += NTHR) wih0s[i] = (f16)wih0[i];
  for (int i = tid; i < 1024; i += NTHR) {
    b0s[i] = (f16)(bih0[i] + bhh0[i]);
    b1s[i] = (f16)(bih1[i] + bhh1[i]);
  }
  for (int i = tid; i < 384; i += NTHR) w2s[i] = ow2[i];
  if (tid < 128) ob1s[tid] = ob1[tid];
  if (tid < 96)  decs[tid] = stok[tid % 3];
  if (tid < 3)   ob2s[tid] = ob2[tid];
  __syncthreads();

  // ---------------- encoder (one-time, fp32 VALU; e buffers plain f16) ----------------
  {
    const int r  = tid >> 4;           // 32 rows, 16 threads each
    const int cb = (tid & 15) << 4;    // 16 cols per thread
    float xr[7];
    #pragma unroll
    for (int k = 0; k < 7; ++k) xr[k] = x[(row0 + r) * 7 + k];
    for (int c16 = 0; c16 < 16; ++c16) {           // e1 -> h1s (plain)
      int c = cb + c16;
      float a = eb1[c];
      #pragma unroll
      for (int k = 0; k < 7; ++k) a += xr[k] * ew1[c * 7 + k];
      h1s[r * HH + c] = (f16)fmaxf(a, 0.0f);
    }
    __syncthreads();
    const f4v* W2v = (const f4v*)ew2;
    for (int c16 = 0; c16 < 16; ++c16) {           // e2 -> h0s (plain)
      int c = cb + c16;
      float a = eb2[c];
      for (int k4 = 0; k4 < 64; ++k4) {
        h4v ev = ((const h4v*)h1s)[(r << 6) + k4];
        f4v w4 = W2v[c * 64 + k4];
        #pragma unroll
        for (int j = 0; j < 4; ++j) a += (float)ev[j] * w4[j];
      }
      h0s[r * HH + c] = (f16)fmaxf(a, 0.0f);
    }
    __syncthreads();
    const f4v* W3v = (const f4v*)ew3;
    float e3v[16];
    for (int c16 = 0; c16 < 16; ++c16) {           // e3 (from h0s) -> regs
      int c = cb + c16;
      float a = eb3[c];
      for (int k4 = 0; k4 < 64; ++k4) {
        h4v ev = ((const h4v*)h0s)[(r << 6) + k4];
        f4v w4 = W3v[c * 64 + k4];
        #pragma unroll
        for (int j = 0; j < 4; ++j) a += (float)ev[j] * w4[j];
      }
      e3v[c16] = fmaxf(a, 0.0f);
    }
    __syncthreads();   // h0s reads done; now overwrite h1s with e3 (plain)
    for (int c16 = 0; c16 < 16; ++c16) h1s[r * HH + cb + c16] = (f16)e3v[c16];
    __syncthreads();
  }

  // ---------------- h/c init from e3 (plain in h1s) ----------------
  float c0v[2][2][4], c1v[2][2][4];     // [hi][mi][j]
  h4v  qv[2][2];                        // sigm(i), f16, [hi][mi]
  f16  h1st[2][8];
  {
    const f4v* HIW4 = (const f4v*)hiw;
    const f4v* CIW4 = (const f4v*)ciw;
    #pragma unroll
    for (int hi = 0; hi < 2; ++hi) {
      const int d = ((wv + 8 * hi) << 4) + lr;     // h-col 0..255
      float aH0[8], aC0[8], aH1[8], aC1[8];
      #pragma unroll
      for (int ri = 0; ri < 8; ++ri) { aH0[ri]=0.f; aC0[ri]=0.f; aH1[ri]=0.f; aC1[ri]=0.f; }
      for (int k4 = 0; k4 < 64; ++k4) {
        f4v wh0 = HIW4[d * 64 + k4];
        f4v wc0 = CIW4[d * 64 + k4];
        f4v wh1 = HIW4[(256 + d) * 64 + k4];
        f4v wc1 = CIW4[(256 + d) * 64 + k4];
        #pragma unroll
        for (int ri = 0; ri < 8; ++ri) {
          const int r = ((ri >> 2) << 4) + (lg << 2) + (ri & 3);
          h4v ev4 = ((const h4v*)h1s)[(r << 6) + k4];
          #pragma unroll
          for (int j = 0; j < 4; ++j) {
            float e = (float)ev4[j];
            aH0[ri] += e * wh0[j];
            aC0[ri] += e * wc0[j];
            aH1[ri] += e * wh1[j];
            aC1[ri] += e * wc1[j];
          }
        }
      }
      const float bh0 = hib[d], bc0 = cib[d], bh1v = hib[256 + d], bc1 = cib[256 + d];
      #pragma unroll
      for (int ri = 0; ri < 8; ++ri) {
        c0v[hi][ri >> 2][ri & 3] = aC0[ri] + bc0;
        c1v[hi][ri >> 2][ri & 3] = aC1[ri] + bc1;
        h1st[hi][ri] = (f16)(aH1[ri] + bh1v);
        const int r = ((ri >> 2) << 4) + (lg << 2) + (ri & 3);
        hstore(h0s, r, d, (f16)(aH0[ri] + bh0));   // h0s held dead e2
      }
    }
  }
  __syncthreads();  // all e3 reads of h1s done
  #pragma unroll
  for (int hi = 0; hi < 2; ++hi) {
    const int d = ((wv + 8 * hi) << 4) + lr;
    #pragma unroll
    for (int ri = 0; ri < 8; ++ri) {
      const int r = ((ri >> 2) << 4) + (lg << 2) + (ri & 3);
      hstore(h1s, r, d, h1st[hi][ri]);
    }
  }
  __syncthreads();

  // ---------------- T = 200 sequential decoder steps ----------------
  for (int t = 0; t < TT; ++t) {
    h4v h0n[2][2], h1n[2][2];

    // ======== layer 0: per-gate phases (i, f, g, o), A = h0s (old) ========
    #pragma unroll
    for (int G = 0; G < 4; ++G) {
      f4v acc[2][2];
      acc[0][0] = fzero(); acc[0][1] = fzero(); acc[1][0] = fzero(); acc[1][1] = fzero();
      GEMM8(acc, h0s, W0, 16 * G + wv, 16 * G + wv + 8);
      #pragma unroll
      for (int hi = 0; hi < 2; ++hi) {
        const int col  = ((wv + 8 * hi) << 4) + lr;
        const int grow = (G << 8) + col;
        const float bX = (float)b0s[grow];
        const float w0_ = (float)wih0s[grow * 3 + 0];
        const float w1_ = (float)wih0s[grow * 3 + 1];
        const float w2_ = (float)wih0s[grow * 3 + 2];
        #pragma unroll
        for (int mi = 0; mi < 2; ++mi)
          #pragma unroll
          for (int j = 0; j < 4; ++j) {
            const int r = (mi << 4) + (lg << 2) + j;
            const float gX = acc[hi][mi][j] + bX
                           + decs[r*3+0]*w0_ + decs[r*3+1]*w1_ + decs[r*3+2]*w2_;
            if (G == 0)      qv[hi][mi][j] = (f16)sigm(gX);
            else if (G == 1) c0v[hi][mi][j] *= sigm(gX);
            else if (G == 2) c0v[hi][mi][j] += (float)qv[hi][mi][j] * tanhfast(gX);
            else             h0n[hi][mi][j] = (f16)(sigm(gX) * tanhfast(c0v[hi][mi][j]));
          }
      }
    }
    __syncthreads();   // all L0 reads of h0s(old) done
    #pragma unroll
    for (int hi = 0; hi < 2; ++hi) {
      const int col = ((wv + 8 * hi) << 4) + lr;
      #pragma unroll
      for (int mi = 0; mi < 2; ++mi)
        #pragma unroll
        for (int j = 0; j < 4; ++j)
          hstore(h0s, (mi << 4) + (lg << 2) + j, col, h0n[hi][mi][j]);
    }
    __syncthreads();   // h0s now holds h0(new)

    // ======== layer 1: per-gate phases, A = h0s(new) @ W1i + h1s(old) @ W1h ========
    #pragma unroll
    for (int G = 0; G < 4; ++G) {
      f4v acc[2][2];
      acc[0][0] = fzero(); acc[0][1] = fzero(); acc[1][0] = fzero(); acc[1][1] = fzero();
      GEMM8(acc, h0s, W1i, 16 * G + wv, 16 * G + wv + 8);
      GEMM8(acc, h1s, W1h, 16 * G + wv, 16 * G + wv + 8);
      #pragma unroll
      for (int hi = 0; hi < 2; ++hi) {
        const int col  = ((wv + 8 * hi) << 4) + lr;
        const int grow = (G << 8) + col;
        const float bX = (float)b1s[grow];
        #pragma unroll
        for (int mi = 0; mi < 2; ++mi)
          #pragma unroll
          for (int j = 0; j < 4; ++j) {
            const float gX = acc[hi][mi][j] + bX;
            if (G == 0)      qv[hi][mi][j] = (f16)sigm(gX);
            else if (G == 1) c1v[hi][mi][j] *= sigm(gX);
            else if (G == 2) c1v[hi][mi][j] += (float)qv[hi][mi][j] * tanhfast(gX);
            else             h1n[hi][mi][j] = (f16)(sigm(gX) * tanhfast(c1v[hi][mi][j]));
          }
      }
    }
    __syncthreads();   // all L1 reads of h1s(old) done
    #pragma unroll
    for (int hi = 0; hi < 2; ++hi) {
      const int col = ((wv + 8 * hi) << 4) + lr;
      #pragma unroll
      for (int mi = 0; mi < 2; ++mi)
        #pragma unroll
        for (int j = 0; j < 4; ++j)
          hstore(h1s, (mi << 4) + (lg << 2) + j, col, h1n[hi][mi][j]);
    }
    __syncthreads();   // h1s now holds h1(new)

    // ======== out head: o1 = relu(h1n @ out_w1^T + b1), n-tile = wv ========
    {
      f4v oa[2];
      oa[0] = fzero(); oa[1] = fzero();
      h8v bo[3];
      bo[0] = OW1[(wv << 9) + (lg << 4) + lr];
      bo[1] = OW1[(wv << 9) + ((4 + lg) << 4) + lr];
      #pragma unroll
      for (int k = 0; k < 8; ++k) {
        if (k < 6) bo[(k + 2) % 3] = OW1[(wv << 9) + ((((k + 2) << 2) + lg) << 4) + lr];
        oa[0] = mfma16(hload8(h1s, lr,      (k << 2) + lg), bo[k % 3], oa[0]);
        oa[1] = mfma16(hload8(h1s, 16 + lr, (k << 2) + lg), bo[k % 3], oa[1]);
      }
      const float obv = ob1s[(wv << 4) + lr];
      #pragma unroll
      for (int mi = 0; mi < 2; ++mi)
        #pragma unroll
        for (int j = 0; j < 4; ++j) {
          const int r = (mi << 4) + (lg << 2) + j;
          o1s[r * OSTR + (wv << 4) + lr] = (f16)fmaxf(oa[mi][j] + obv, 0.0f);
        }
    }
    __syncthreads();

    // ======== final: out = o1 @ out_w2^T + b2 ; feed back as dec ========
    {
      const int r  = tid >> 4;          // 32 rows x 16 threads
      const int jj = tid & 15;          // 8-wide k chunk each
      float a0 = 0.f, a1 = 0.f, a2 = 0.f;
      #pragma unroll
      for (int kk = 0; kk < 8; ++kk) {
        const int k = (jj << 3) + kk;
        const float ov = (float)o1s[r * OSTR + k];
        a0 += ov * w2s[k];
        a1 += ov * w2s[128 + k];
        a2 += ov * w2s[256 + k];
      }
      #pragma unroll
      for (int s = 8; s >= 1; s >>= 1) {
        a0 += __shfl_xor(a0, s);
        a1 += __shfl_xor(a1, s);
        a2 += __shfl_xor(a2, s);
      }
      if (jj == 0) {
        a0 += ob2s[0]; a1 += ob2s[1]; a2 += ob2s[2];
        float* op = out + ((size_t)(row0 + r) * TT + t) * 3;
        op[0] = a0; op[1] = a1; op[2] = a2;
        decs[r * 3 + 0] = a0; decs[r * 3 + 1] = a1; decs[r * 3 + 2] = a2;
      }
    }
    __syncthreads();
  }
}

extern "C" void kernel_launch(void* const* d_in, const int* in_sizes, int n_in,
                              void* d_out, int out_size, void* d_ws, size_t ws_size,
                              hipStream_t stream) {
  (void)in_sizes; (void)n_in; (void)out_size; (void)ws_size;
  f16* wk = (f16*)d_ws;
  conv_w<<<3200, 256, 0, stream>>>((const float*)d_in[12], (const float*)d_in[15],
                                   (const float*)d_in[16], (const float*)d_in[19], wk);
  traj_kernel<<<NWG, NTHR, 0, stream>>>(
      (const float*)d_in[0],
      (const float*)d_in[1],  (const float*)d_in[2],
      (const float*)d_in[3],  (const float*)d_in[4],
      (const float*)d_in[5],  (const float*)d_in[6],
      (const float*)d_in[7],  (const float*)d_in[8],
      (const float*)d_in[9],  (const float*)d_in[10],
      (const float*)d_in[11],
      (const float*)d_in[13], (const float*)d_in[14],
      (const float*)d_in[17], (const float*)d_in[18],
      (const float*)d_in[20], (const float*)d_in[21],
      (const float*)d_in[22], (const float*)d_in[23],
      wk, (float*)d_out);
}

// Round 5
// 20749.529 us; speedup vs baseline: 1.2580x; 1.1663x over previous
//
#include <hip/hip_runtime.h>

typedef _Float16 f16;
typedef f16 h8v __attribute__((ext_vector_type(8)));
typedef f16 h4v __attribute__((ext_vector_type(4)));
typedef float f4v __attribute__((ext_vector_type(4)));

#define ROWS 32
#define HH 256
#define TT 200
#define NTHR 512
#define NWG 256
#define OSTR 132
#define CHUNK 16384   // f16 elems per 32KB weight chunk (4 n-tiles)

static __device__ __forceinline__ f4v mfma16(h8v a, h8v b, f4v c) {
  return __builtin_amdgcn_mfma_f32_16x16x32_f16(a, b, c, 0, 0, 0);
}
static __device__ __forceinline__ f4v fzero() { f4v z; z[0]=0.f; z[1]=0.f; z[2]=0.f; z[3]=0.f; return z; }
static __device__ __forceinline__ float sigm(float x) { return 1.0f / (1.0f + __expf(-x)); }
static __device__ __forceinline__ float tanhfast(float x) {
  float t = __expf(-2.0f * fabsf(x));
  float r = (1.0f - t) / (1.0f + t);
  return copysignf(r, x);
}
// swizzled f16 [32][256] LDS tile: 16B chunks XORed by row&7 -> conflict-free ds_read_b128
static __device__ __forceinline__ void hstore(f16* hs, int r, int d, f16 v) {
  hs[r * HH + ((((d >> 3) ^ (r & 7)) << 3) | (d & 7))] = v;
}
static __device__ __forceinline__ h8v hload8(const f16* hs, int r, int kc) {
  return ((const h8v*)hs)[r * 32 + (kc ^ (r & 7))];
}

// Pre-convert + fragment-order swizzle the 4 streamed weight matrices to f16 in ws.
// Layout per matrix: [n_tile][k_chunk(32)][row_in_tile(16)] of h8v (8KB per n-tile).
__global__ void conv_w(const float* __restrict__ whh0, const float* __restrict__ wih1,
                       const float* __restrict__ whh1, const float* __restrict__ ow1,
                       f16* __restrict__ dst) {
  int i = blockIdx.x * 256 + threadIdx.x;  // 0 .. 819199
  const float* src;
  int base;
  if (i < 262144)      { src = whh0; base = 0; }
  else if (i < 524288) { src = wih1; base = 262144; }
  else if (i < 786432) { src = whh1; base = 524288; }
  else                 { src = ow1;  base = 786432; }
  int e = i - base;
  int row = e >> 8, col = e & 255;
  int idx = base + ((((row >> 4) << 5) + (col >> 3)) << 7) + ((row & 15) << 3) + (col & 7);
  dst[idx] = (f16)src[e];
}

// Consumption sequence (period 50): s<16: W0 chunk s; s in [16,48): pairs (W1i, W1h)
// chunk (s-16)>>1; s in [48,50): OW1 chunk s-48.  Chunk = 4 n-tiles = 16384 f16.
static __device__ __forceinline__ const f16* chunk_ptr(const f16* wk, int s) {
  int a;
  if (s < 16)      a = s << 14;
  else if (s < 48) { const int u = s - 16; a = ((1 + (u & 1)) << 18) + ((u >> 1) << 14); }
  else             a = (3 << 18) + ((s - 48) << 14);
  return wk + a;
}

// Cooperative async copy of one 32KB chunk: 8 waves x 4 issues x (64 lanes x 16B).
// LDS dest is wave-uniform base; HW adds lane*16.
static __device__ __forceinline__ void issue_chunk(const f16* g, f16* l, int wv, int lane) {
#pragma unroll
  for (int rr = 0; rr < 4; ++rr) {
    const f16* gp = g + (wv << 11) + (rr << 9) + (lane << 3);
    f16* lp = l + (wv << 11) + (rr << 9);
    __builtin_amdgcn_global_load_lds((const __attribute__((address_space(1))) void*)gp,
                                     (__attribute__((address_space(3))) void*)lp,
                                     16, 0, 0);
  }
}

#define BARSYNC() asm volatile("s_waitcnt lgkmcnt(0)\n\ts_barrier" ::: "memory")
#define WAITV()   asm volatile("s_waitcnt vmcnt(4)" ::: "memory")
#define ADVP()    do { si = (si == 49) ? 0 : si + 1; cb = (cb == 2) ? 0 : cb + 1; } while (0)
#define ISSUE_NEXT()                                                     \
  do { int ib_ = cb + 2; if (ib_ >= 3) ib_ -= 3;                         \
       issue_chunk(chunk_ptr(wk, si), stage + ib_ * CHUNK, wv, lane); } while (0)

__global__ __launch_bounds__(NTHR, 1)
void traj_kernel(const float* __restrict__ x,
                 const float* __restrict__ ew1, const float* __restrict__ eb1,
                 const float* __restrict__ ew2, const float* __restrict__ eb2,
                 const float* __restrict__ ew3, const float* __restrict__ eb3,
                 const float* __restrict__ hiw, const float* __restrict__ hib,
                 const float* __restrict__ ciw, const float* __restrict__ cib,
                 const float* __restrict__ wih0,
                 const float* __restrict__ bih0, const float* __restrict__ bhh0,
                 const float* __restrict__ bih1, const float* __restrict__ bhh1,
                 const float* __restrict__ ob1, const float* __restrict__ ow2,
                 const float* __restrict__ ob2, const float* __restrict__ stok,
                 const f16* __restrict__ wk, float* __restrict__ out)
{
  __shared__ __align__(16) f16 stage[3 * CHUNK];  // 96 KB triple-buffered weight chunks
  __shared__ __align__(16) f16 h0s[ROWS * HH];    // 16 KB swizzled h0 (e2 during setup)
  __shared__ __align__(16) f16 h1s[ROWS * HH];    // 16 KB swizzled h1 (e1/e3 during setup)
  __shared__ f16 o1s[ROWS * OSTR];                // 8.25 KB
  __shared__ f16 wih0s[1024 * 3];                 // 6 KB
  __shared__ f16 b0s[1024];                       // 2 KB (b_ih0 + b_hh0)
  __shared__ f16 b1s[1024];                       // 2 KB
  __shared__ float w2s[3 * 128];                  // 1.5 KB
  __shared__ float ob1s[128];
  __shared__ float decs[ROWS * 3];
  __shared__ float ob2s[4];

  const int tid  = threadIdx.x;
  const int wv   = tid >> 6;
  const int lane = tid & 63;
  const int lr   = lane & 15;
  const int lg   = lane >> 4;
  const int ntl  = wv >> 1;   // n-tile index within 4-tile chunk
  const int mt   = wv & 1;    // m-tile (rows 16*mt .. 16*mt+15)
  const int row0 = blockIdx.x * ROWS;

  // ---- stage small constants ----
  for (int i = tid; i < 3072; i += NTHR) wih0s[i] = (f16)wih0[i];
  for (int i = tid; i < 1024; i += NTHR) {
    b0s[i] = (f16)(bih0[i] + bhh0[i]);
    b1s[i] = (f16)(bih1[i] + bhh1[i]);
  }
  for (int i = tid; i < 384; i += NTHR) w2s[i] = ow2[i];
  if (tid < 128) ob1s[tid] = ob1[tid];
  if (tid < 96)  decs[tid] = stok[tid % 3];
  if (tid < 3)   ob2s[tid] = ob2[tid];
  __syncthreads();

  // ---------------- encoder (one-time, fp32 VALU; e buffers plain f16) ----------------
  {
    const int r  = tid >> 4;           // 32 rows, 16 threads each
    const int cb2 = (tid & 15) << 4;   // 16 cols per thread
    float xr[7];
    #pragma unroll
    for (int k = 0; k < 7; ++k) xr[k] = x[(row0 + r) * 7 + k];
    for (int c16 = 0; c16 < 16; ++c16) {           // e1 -> h1s (plain)
      int c = cb2 + c16;
      float a = eb1[c];
      #pragma unroll
      for (int k = 0; k < 7; ++k) a += xr[k] * ew1[c * 7 + k];
      h1s[r * HH + c] = (f16)fmaxf(a, 0.0f);
    }
    __syncthreads();
    const f4v* W2v = (const f4v*)ew2;
    for (int c16 = 0; c16 < 16; ++c16) {           // e2 -> h0s (plain)
      int c = cb2 + c16;
      float a = eb2[c];
      for (int k4 = 0; k4 < 64; ++k4) {
        h4v ev = ((const h4v*)h1s)[(r << 6) + k4];
        f4v w4 = W2v[c * 64 + k4];
        #pragma unroll
        for (int j = 0; j < 4; ++j) a += (float)ev[j] * w4[j];
      }
      h0s[r * HH + c] = (f16)fmaxf(a, 0.0f);
    }
    __syncthreads();
    const f4v* W3v = (const f4v*)ew3;
    float e3v[16];
    for (int c16 = 0; c16 < 16; ++c16) {           // e3 (from h0s=e2) -> regs
      int c = cb2 + c16;
      float a = eb3[c];
      for (int k4 = 0; k4 < 64; ++k4) {
        h4v ev = ((const h4v*)h0s)[(r << 6) + k4];
        f4v w4 = W3v[c * 64 + k4];
        #pragma unroll
        for (int j = 0; j < 4; ++j) a += (float)ev[j] * w4[j];
      }
      e3v[c16] = fmaxf(a, 0.0f);
    }
    __syncthreads();
    for (int c16 = 0; c16 < 16; ++c16) h1s[r * HH + cb2 + c16] = (f16)e3v[c16];
    __syncthreads();
  }

  // ---------------- h/c init from e3 (plain in h1s) ----------------
  // Thread ownership (matches step loop): cols (4p+ntl)*16+lr (p=0..3), rows 16mt+4lg+j.
  float c0v[4][4], c1v[4][4];
  h4v qv[4];
  {
    const f4v* HIW4 = (const f4v*)hiw;
    const f4v* CIW4 = (const f4v*)ciw;
    f16 h1tmp[4][4];
#pragma unroll
    for (int p = 0; p < 4; ++p) {
      const int d = (((p << 2) + ntl) << 4) + lr;
      float aH0[4] = {0.f,0.f,0.f,0.f}, aC0[4] = {0.f,0.f,0.f,0.f};
      float aH1[4] = {0.f,0.f,0.f,0.f}, aC1[4] = {0.f,0.f,0.f,0.f};
      for (int k4 = 0; k4 < 64; ++k4) {
        const f4v wh0 = HIW4[d * 64 + k4];
        const f4v wc0 = CIW4[d * 64 + k4];
        const f4v wh1 = HIW4[(256 + d) * 64 + k4];
        const f4v wc1 = CIW4[(256 + d) * 64 + k4];
#pragma unroll
        for (int j = 0; j < 4; ++j) {
          const int r = (mt << 4) + (lg << 2) + j;
          const h4v ev4 = ((const h4v*)h1s)[(r << 6) + k4];
#pragma unroll
          for (int e = 0; e < 4; ++e) {
            const float ev = (float)ev4[e];
            aH0[j] += ev * wh0[e];
            aC0[j] += ev * wc0[e];
            aH1[j] += ev * wh1[e];
            aC1[j] += ev * wc1[e];
          }
        }
      }
      const float bh0 = hib[d], bc0 = cib[d], bh1v = hib[256 + d], bc1 = cib[256 + d];
#pragma unroll
      for (int j = 0; j < 4; ++j) {
        c0v[p][j] = aC0[j] + bc0;
        c1v[p][j] = aC1[j] + bc1;
        h1tmp[p][j] = (f16)(aH1[j] + bh1v);
        const int r = (mt << 4) + (lg << 2) + j;
        hstore(h0s, r, d, (f16)(aH0[j] + bh0));    // h0s held dead e2
      }
    }
    __syncthreads();  // all e3 reads of h1s done
#pragma unroll
    for (int p = 0; p < 4; ++p) {
      const int d = (((p << 2) + ntl) << 4) + lr;
#pragma unroll
      for (int j = 0; j < 4; ++j) {
        const int r = (mt << 4) + (lg << 2) + j;
        hstore(h1s, r, d, h1tmp[p][j]);
      }
    }
    __syncthreads();
  }

  // ---- prologue: start the async weight pipeline (chunks 0,1 in flight) ----
  issue_chunk(chunk_ptr(wk, 0), stage,         wv, lane);
  issue_chunk(chunk_ptr(wk, 1), stage + CHUNK, wv, lane);
  int si = 2;   // next seq index to issue (phase k issues k+2, mod 50)
  int cb = 0;   // buffer holding current chunk (= phase mod 3)

  float dv0[4], dv1[4], dv2[4];
  h8v aR[8];

  // ---------------- T = 200 sequential decoder steps ----------------
#pragma unroll 1
  for (int t = 0; t < TT; ++t) {
    // stage 1: A <- h0(old); dec -> regs
#pragma unroll
    for (int k = 0; k < 8; ++k) aR[k] = hload8(h0s, (mt << 4) + lr, (k << 2) + lg);
#pragma unroll
    for (int j = 0; j < 4; ++j) {
      const int r = (mt << 4) + (lg << 2) + j;
      dv0[j] = decs[r * 3 + 0];
      dv1[j] = decs[r * 3 + 1];
      dv2[j] = decs[r * 3 + 2];
    }
    BARSYNC();   // everyone done reading h0s(old) + decs

    // ======== layer 0: 16 chunk-phases (gate G, sub p) ========
#pragma unroll
    for (int G = 0; G < 4; ++G) {
#pragma unroll
      for (int p = 0; p < 4; ++p) {
        WAITV(); BARSYNC();
        ISSUE_NEXT();
        const h8v* SB = (const h8v*)(stage + cb * CHUNK);
        f4v accA = fzero(), accB = fzero();
#pragma unroll
        for (int k = 0; k < 8; k += 2) {
          accA = mfma16(aR[k],     SB[(ntl << 9) + (((k << 2) + lg) << 4) + lr], accA);
          accB = mfma16(aR[k + 1], SB[(ntl << 9) + ((((k + 1) << 2) + lg) << 4) + lr], accB);
        }
        const int grow = (((G << 4) + (p << 2) + ntl) << 4) + lr;
        const float bX = (float)b0s[grow];
        const float u0 = (float)wih0s[grow * 3 + 0];
        const float u1 = (float)wih0s[grow * 3 + 1];
        const float u2 = (float)wih0s[grow * 3 + 2];
#pragma unroll
        for (int j = 0; j < 4; ++j) {
          const float gX = accA[j] + accB[j] + bX + dv0[j]*u0 + dv1[j]*u1 + dv2[j]*u2;
          if (G == 0)      qv[p][j] = (f16)sigm(gX);
          else if (G == 1) c0v[p][j] *= sigm(gX);
          else if (G == 2) c0v[p][j] += (float)qv[p][j] * tanhfast(gX);
          else {
            const int r = (mt << 4) + (lg << 2) + j;
            hstore(h0s, r, (((p << 2) + ntl) << 4) + lr,
                   (f16)(sigm(gX) * tanhfast(c0v[p][j])));
          }
        }
        ADVP();
      }
    }
    BARSYNC();   // h0(new) visible

    // stage 4: A <- h1(old)
#pragma unroll
    for (int k = 0; k < 8; ++k) aR[k] = hload8(h1s, (mt << 4) + lr, (k << 2) + lg);
    BARSYNC();   // all h1s(old) reads complete before L1 G=3 writes

    // ======== layer 1: 16 pairs (W1i phase A=h0s-LDS, W1h phase A=aR) ========
#pragma unroll
    for (int i = 0; i < 16; ++i) {
      f4v accA = fzero(), accB = fzero();
      WAITV(); BARSYNC();
      ISSUE_NEXT();
      {
        const h8v* SB = (const h8v*)(stage + cb * CHUNK);
#pragma unroll
        for (int k = 0; k < 8; k += 2) {
          h8v a0 = hload8(h0s, (mt << 4) + lr, (k << 2) + lg);
          h8v a1 = hload8(h0s, (mt << 4) + lr, ((k + 1) << 2) + lg);
          accA = mfma16(a0, SB[(ntl << 9) + (((k << 2) + lg) << 4) + lr], accA);
          accB = mfma16(a1, SB[(ntl << 9) + ((((k + 1) << 2) + lg) << 4) + lr], accB);
        }
      }
      ADVP();
      WAITV(); BARSYNC();
      ISSUE_NEXT();
      {
        const h8v* SB = (const h8v*)(stage + cb * CHUNK);
#pragma unroll
        for (int k = 0; k < 8; k += 2) {
          accA = mfma16(aR[k],     SB[(ntl << 9) + (((k << 2) + lg) << 4) + lr], accA);
          accB = mfma16(aR[k + 1], SB[(ntl << 9) + ((((k + 1) << 2) + lg) << 4) + lr], accB);
        }
      }
      const int G = i >> 2, p = i & 3;
      const int grow = (((G << 4) + (p << 2) + ntl) << 4) + lr;
      const float bX = (float)b1s[grow];
#pragma unroll
      for (int j = 0; j < 4; ++j) {
        const float gX = accA[j] + accB[j] + bX;
        if (G == 0)      qv[p][j] = (f16)sigm(gX);
        else if (G == 1) c1v[p][j] *= sigm(gX);
        else if (G == 2) c1v[p][j] += (float)qv[p][j] * tanhfast(gX);
        else {
          const int r = (mt << 4) + (lg << 2) + j;
          hstore(h1s, r, (((p << 2) + ntl) << 4) + lr,
                 (f16)(sigm(gX) * tanhfast(c1v[p][j])));
        }
      }
      ADVP();
    }
    BARSYNC();   // h1(new) visible

    // stage 6: A <- h1(new) for head
#pragma unroll
    for (int k = 0; k < 8; ++k) aR[k] = hload8(h1s, (mt << 4) + lr, (k << 2) + lg);

    // ======== out head: 2 chunk-phases ========
#pragma unroll
    for (int p = 0; p < 2; ++p) {
      WAITV(); BARSYNC();
      ISSUE_NEXT();
      const h8v* SB = (const h8v*)(stage + cb * CHUNK);
      f4v accA = fzero(), accB = fzero();
#pragma unroll
      for (int k = 0; k < 8; k += 2) {
        accA = mfma16(aR[k],     SB[(ntl << 9) + (((k << 2) + lg) << 4) + lr], accA);
        accB = mfma16(aR[k + 1], SB[(ntl << 9) + ((((k + 1) << 2) + lg) << 4) + lr], accB);
      }
      const int col = (((p << 2) + ntl) << 4) + lr;
      const float obv = ob1s[col];
#pragma unroll
      for (int j = 0; j < 4; ++j) {
        const int r = (mt << 4) + (lg << 2) + j;
        o1s[r * OSTR + col] = (f16)fmaxf(accA[j] + accB[j] + obv, 0.0f);
      }
      ADVP();
    }
    BARSYNC();   // o1s visible

    // ======== final: out = o1 @ out_w2^T + b2 ; feed back as dec ========
    {
      const int r  = tid >> 4;          // 32 rows x 16 threads
      const int jj = tid & 15;          // 8-wide k chunk each
      float a0 = 0.f, a1 = 0.f, a2 = 0.f;
#pragma unroll
      for (int kk = 0; kk < 8; ++kk) {
        const int k = (jj << 3) + kk;
        const float ov = (float)o1s[r * OSTR + k];
        a0 += ov * w2s[k];
        a1 += ov * w2s[128 + k];
        a2 += ov * w2s[256 + k];
      }
#pragma unroll
      for (int s = 8; s >= 1; s >>= 1) {
        a0 += __shfl_xor(a0, s);
        a1 += __shfl_xor(a1, s);
        a2 += __shfl_xor(a2, s);
      }
      if (jj == 0) {
        a0 += ob2s[0]; a1 += ob2s[1]; a2 += ob2s[2];
        float* op = out + ((size_t)(row0 + r) * TT + t) * 3;
        op[0] = a0; op[1] = a1; op[2] = a2;
        decs[r * 3 + 0] = a0; decs[r * 3 + 1] = a1; decs[r * 3 + 2] = a2;
      }
    }
    BARSYNC();   // decs visible for next step
  }
}

extern "C" void kernel_launch(void* const* d_in, const int* in_sizes, int n_in,
                              void* d_out, int out_size, void* d_ws, size_t ws_size,
                              hipStream_t stream) {
  (void)in_sizes; (void)n_in; (void)out_size; (void)ws_size;
  f16* wk = (f16*)d_ws;
  conv_w<<<3200, 256, 0, stream>>>((const float*)d_in[12], (const float*)d_in[15],
                                   (const float*)d_in[16], (const float*)d_in[19], wk);
  traj_kernel<<<NWG, NTHR, 0, stream>>>(
      (const float*)d_in[0],
      (const float*)d_in[1],  (const float*)d_in[2],
      (const float*)d_in[3],  (const float*)d_in[4],
      (const float*)d_in[5],  (const float*)d_in[6],
      (const float*)d_in[7],  (const float*)d_in[8],
      (const float*)d_in[9],  (const float*)d_in[10],
      (const float*)d_in[11],
      (const float*)d_in[13], (const float*)d_in[14],
      (const float*)d_in[17], (const float*)d_in[18],
      (const float*)d_in[20], (const float*)d_in[21],
      (const float*)d_in[22], (const float*)d_in[23],
      wk, (float*)d_out);
}

// Round 8
// 11037.658 us; speedup vs baseline: 2.3650x; 1.8799x over previous
//
#include <hip/hip_runtime.h>

typedef _Float16 f16;
typedef f16 h8v __attribute__((ext_vector_type(8)));
typedef f16 h4v __attribute__((ext_vector_type(4)));
typedef float f4v __attribute__((ext_vector_type(4)));

#define TT 200
#define NTHR 512
#define NWG 256

// ---- d_ws layout (f16-element offsets) ----
#define W0F   0          // w_hh0  frag [64 tiles][512 h8v]
#define W1IF  262144     // w_ih1
#define W1HF  524288     // w_hh1
#define OW1F  786432     // out_w1 frag [8 tiles]
#define EW2F  819200     // enc_w2 frag [16 tiles]
#define EW3F  884736     // enc_w3 frag [16 tiles]
#define HIWF  950272     // hinit_w frag [32 tiles]
#define CIWF  1081344    // cinit_w frag [32 tiles]
#define FRAG_TOTAL 1212416  // == CIWF + 131072; conv_w must cover ALL of it
#define H0F   1212416    // h0 state [2 parity][16 g][16 m][512][16] f16
#define H1F   5406720    // h1 state (same shape)
#define O1F   9601024    // o1 [16 g][8 tile][512][16] f16
#define DECF  10649600   // dec [16 g][2 parity][512][4] FLOAT (occupies 131072 f16 units)
#define FLGF  10780672   // int32 flags [16 g][8] at byte offset FLGF*2

// flag indices
#define FE1 0
#define FE2 1
#define FE3 2
#define FDEC 3
#define FH0 4
#define FH1 5
#define FO1 6

static __device__ __forceinline__ f4v mfma16(h8v a, h8v b, f4v c) {
  return __builtin_amdgcn_mfma_f32_16x16x32_f16(a, b, c, 0, 0, 0);
}
static __device__ __forceinline__ f4v fzero() { f4v z; z[0]=0.f; z[1]=0.f; z[2]=0.f; z[3]=0.f; return z; }
static __device__ __forceinline__ float sigm(float x) { return 1.0f / (1.0f + __expf(-x)); }
static __device__ __forceinline__ float tanhfast(float x) {
  float t = __expf(-2.0f * fabsf(x));
  float r = (1.0f - t) / (1.0f + t);
  return copysignf(r, x);
}

// Fragment-order convert all 8 weight matrices (layout [tile][kc 32][lr 16] of h8v)
// and zero the group flags. Runs as its own dispatch each launch.
// ROUND-8 FIX: grid must cover FRAG_TOTAL = 1,212,416 elements; round 6/7 launched
// 4608 blocks = 1,179,648 and left cinit tiles 24-31 (c1-init weights for h-dims
// 128-255, used by members 8-15) as 0xAA poison -> deterministic absmax 0.386.
__global__ void conv_w(const float* __restrict__ whh0, const float* __restrict__ wih1,
                       const float* __restrict__ whh1, const float* __restrict__ ow1,
                       const float* __restrict__ ew2,  const float* __restrict__ ew3,
                       const float* __restrict__ hiw,  const float* __restrict__ ciw,
                       f16* __restrict__ dst, int* __restrict__ flags) {
  int i = blockIdx.x * 256 + threadIdx.x;   // 0 .. FRAG_TOTAL-1
  if (blockIdx.x == 0 && threadIdx.x < 128) flags[threadIdx.x] = 0;
  if (i >= FRAG_TOTAL) return;
  const float* src; int base;
  if      (i < 262144)  { src = whh0; base = 0; }
  else if (i < 524288)  { src = wih1; base = 262144; }
  else if (i < 786432)  { src = whh1; base = 524288; }
  else if (i < 819200)  { src = ow1;  base = 786432; }
  else if (i < 884736)  { src = ew2;  base = 819200; }
  else if (i < 950272)  { src = ew3;  base = 884736; }
  else if (i < 1081344) { src = hiw;  base = 950272; }
  else                  { src = ciw;  base = 1081344; }
  int e = i - base;
  int row = e >> 8, col = e & 255;
  int idx = base + ((((row >> 4) << 5) + (col >> 3)) << 7) + ((row & 15) << 3) + (col & 7);
  dst[idx] = (f16)src[e];
}

// group-flag protocol: cumulative counters, release/acquire at SYSTEM scope so the
// payload (plain stores by all WG threads, ordered via the barrier) is written back
// past the per-XCD L2 on release and re-fetched fresh on acquire (G16).
#define RELF(fi)                                                               \
  do { __syncthreads();                                                        \
       if (tid == 0) __hip_atomic_fetch_add(&flg[fi], 1, __ATOMIC_RELEASE,     \
                                            __HIP_MEMORY_SCOPE_SYSTEM);        \
  } while (0)
#define WAITF(fi, tgt)                                                         \
  do { if (tid == 0) {                                                         \
         while (__hip_atomic_load(&flg[fi], __ATOMIC_RELAXED,                  \
                                  __HIP_MEMORY_SCOPE_SYSTEM) < (tgt))          \
           __builtin_amdgcn_s_sleep(2);                                        \
         (void)__hip_atomic_load(&flg[fi], __ATOMIC_ACQUIRE,                   \
                                 __HIP_MEMORY_SCOPE_SYSTEM);                   \
       }                                                                       \
       __syncthreads();                                                        \
  } while (0)

__global__ __launch_bounds__(NTHR, 1)
void traj_kernel(const float* __restrict__ x,
                 const float* __restrict__ ew1, const float* __restrict__ eb1,
                 const float* __restrict__ eb2, const float* __restrict__ eb3,
                 const float* __restrict__ hib, const float* __restrict__ cib,
                 const float* __restrict__ wih0,
                 const float* __restrict__ bih0, const float* __restrict__ bhh0,
                 const float* __restrict__ bih1, const float* __restrict__ bhh1,
                 const float* __restrict__ ob1, const float* __restrict__ ow2,
                 const float* __restrict__ ob2, const float* __restrict__ stok,
                 f16* __restrict__ ws, int* __restrict__ flags,
                 float* __restrict__ out)
{
  __shared__ __align__(16) f16 WL[13 * 4096];    // 104 KB: 13 LDS-resident weight tiles
  __shared__ __align__(16) float decsL[512 * 4]; // 8 KB dec stage (f32)
  __shared__ __align__(16) f16 o1s[32 * 136];    // 8.5 KB o1 gather
  __shared__ float w2s[384];
  __shared__ float ob2s[4];

  const int tid  = threadIdx.x;
  const int bid  = blockIdx.x;
  // group layout chosen so members share bid%8 (XCD-affine if dispatch is round-robin;
  // correctness does not depend on it with SYSTEM-scope sync)
  const int g    = (bid & 7) + ((bid >> 7) << 3);   // 0..15
  const int m    = (bid >> 3) & 15;                 // member 0..15
  const int wv   = tid >> 6;
  const int lane = tid & 63;
  const int lr   = lane & 15;
  const int lg   = lane >> 4;

  int* flg = flags + g * 8;
  const int dcol = 16 * m + lr;                 // member h-dim for this lane

  f16* e1g = ws + H0F + g * 131072;             // parity-0 h0 area (reused)
  f16* e2g = ws + H1F + g * 131072;             // parity-0 h1 area (reused)
  f16* e3g = ws + H0F + (16 + g) * 131072;      // parity-1 h0 area (reused)
  f16* o1g = ws + O1F + g * 65536;
  float* decb = (float*)(ws + DECF) + g * 4096; // [2 parity][512][4] f32

  // ---- per-lane constants ----
  float wihr[4][3], b0r[4], b1r[4];
#pragma unroll
  for (int G = 0; G < 4; ++G) {
    const int gc = G * 256 + dcol;
    wihr[G][0] = wih0[gc * 3 + 0];
    wihr[G][1] = wih0[gc * 3 + 1];
    wihr[G][2] = wih0[gc * 3 + 2];
    b0r[G] = bih0[gc] + bhh0[gc];
    b1r[G] = bih1[gc] + bhh1[gc];
  }
  const float ob1r = ob1[((m & 7) << 4) + lr];
  if (tid < 384) w2s[tid] = ow2[tid];
  if (tid < 3)   ob2s[tid] = ob2[tid];

  auto cptile = [&](int slot, int srcF) {
    ((h8v*)(WL + slot * 4096))[tid] = *(const h8v*)(ws + srcF + tid * 8);
  };
  auto BF = [&](int slot, int k) -> h8v {          // B-fragment ds_read_b128
    return ((const h8v*)WL)[slot * 512 + ((k << 2) + lg) * 16 + lr];
  };
  auto loadA8 = [&](const f16* gb, int R0, h8v* a) { // A-frags direct global->VGPR
    const f16* p0 = gb + (lg >> 1) * 8192 + (size_t)(R0 + lr) * 16 + (lg & 1) * 8;
#pragma unroll
    for (int k = 0; k < 8; ++k) a[k] = *(const h8v*)(p0 + k * 16384);
  };

  // ================= setup: encoder + h/c init (exchange-based) =================
  cptile(0, EW2F + m * 4096);
  cptile(1, EW3F + m * 4096);
  cptile(2, HIWF + m * 4096);
  cptile(3, HIWF + (16 + m) * 4096);
  cptile(4, CIWF + m * 4096);
  cptile(5, CIWF + (16 + m) * 4096);
  __syncthreads();

  { // e1 (VALU): thread = row, member cols 16m..16m+15
    const int r = tid;
    float xr[7];
#pragma unroll
    for (int k = 0; k < 7; ++k) xr[k] = x[(size_t)(g * 512 + r) * 7 + k];
    f16 ev[16];
#pragma unroll
    for (int i2 = 0; i2 < 16; ++i2) {
      const int c = 16 * m + i2;
      float a = eb1[c];
#pragma unroll
      for (int k = 0; k < 7; ++k) a += xr[k] * ew1[c * 7 + k];
      ev[i2] = (f16)fmaxf(a, 0.0f);
    }
    *(h8v*)(e1g + m * 8192 + r * 16)     = *(h8v*)&ev[0];
    *(h8v*)(e1g + m * 8192 + r * 16 + 8) = *(h8v*)&ev[8];
  }
  RELF(FE1); WAITF(FE1, 16);

  { // e2 = relu(e1 @ ew2^T)
    const float bb = eb2[dcol];
#pragma unroll
    for (int mt = 0; mt < 4; ++mt) {
      const int R0 = wv * 64 + mt * 16;
      h8v a[8]; loadA8(e1g, R0, a);
      f4v acc = fzero();
#pragma unroll
      for (int k = 0; k < 8; ++k) acc = mfma16(a[k], BF(0, k), acc);
#pragma unroll
      for (int j = 0; j < 4; ++j)
        e2g[m * 8192 + (R0 + 4 * lg + j) * 16 + lr] = (f16)fmaxf(acc[j] + bb, 0.0f);
    }
  }
  RELF(FE2); WAITF(FE2, 16);

  { // e3 = relu(e2 @ ew3^T)
    const float bb = eb3[dcol];
#pragma unroll
    for (int mt = 0; mt < 4; ++mt) {
      const int R0 = wv * 64 + mt * 16;
      h8v a[8]; loadA8(e2g, R0, a);
      f4v acc = fzero();
#pragma unroll
      for (int k = 0; k < 8; ++k) acc = mfma16(a[k], BF(1, k), acc);
#pragma unroll
      for (int j = 0; j < 4; ++j)
        e3g[m * 8192 + (R0 + 4 * lg + j) * 16 + lr] = (f16)fmaxf(acc[j] + bb, 0.0f);
    }
  }
  RELF(FE3); WAITF(FE3, 16);

  // h/c init from e3
  float c0v[4][4], c1v[4][4];
  {
    f16* h0g0 = ws + H0F + g * 131072;   // e1 area, dead
    f16* h1g0 = ws + H1F + g * 131072;   // e2 area, dead
    const float bh0 = hib[dcol], bh1 = hib[256 + dcol];
    const float bc0 = cib[dcol], bc1 = cib[256 + dcol];
#pragma unroll
    for (int mt = 0; mt < 4; ++mt) {
      const int R0 = wv * 64 + mt * 16;
      h8v a[8]; loadA8(e3g, R0, a);
      f4v aH = fzero(), aC = fzero();
#pragma unroll
      for (int k = 0; k < 8; ++k) { aH = mfma16(a[k], BF(2, k), aH); aC = mfma16(a[k], BF(4, k), aC); }
#pragma unroll
      for (int j = 0; j < 4; ++j) {
        h0g0[m * 8192 + (R0 + 4 * lg + j) * 16 + lr] = (f16)(aH[j] + bh0);
        c0v[mt][j] = aC[j] + bc0;
      }
      aH = fzero(); aC = fzero();
#pragma unroll
      for (int k = 0; k < 8; ++k) { aH = mfma16(a[k], BF(3, k), aH); aC = mfma16(a[k], BF(5, k), aC); }
#pragma unroll
      for (int j = 0; j < 4; ++j) {
        h1g0[m * 8192 + (R0 + 4 * lg + j) * 16 + lr] = (f16)(aH[j] + bh1);
        c1v[mt][j] = aC[j] + bc1;
      }
    }
    if (tid < 32) { // dec(0) = start_token for member's 32 rows (parity 0, f32)
      f4v d; d[0] = stok[0]; d[1] = stok[1]; d[2] = stok[2]; d[3] = 0.f;
      *(f4v*)(decb + (m * 32 + tid) * 4) = d;
    }
  }
  RELF(FDEC);

  // load the permanent weight tiles (overwrites setup tiles; RELF barrier protects)
#pragma unroll
  for (int G = 0; G < 4; ++G) {
    cptile(G,     W0F  + (G * 16 + m) * 4096);
    cptile(4 + G, W1IF + (G * 16 + m) * 4096);
    cptile(8 + G, W1HF + (G * 16 + m) * 4096);
  }
  cptile(12, OW1F + (m & 7) * 4096);
  __syncthreads();

  // ================= T = 200 sequential decoder steps =================
#pragma unroll 1
  for (int t = 0; t < TT; ++t) {
    const int p = t & 1;
    f16* h0old = ws + H0F + (p * 16 + g) * 131072;
    f16* h0new = ws + H0F + ((p ^ 1) * 16 + g) * 131072;
    f16* h1old = ws + H1F + (p * 16 + g) * 131072;
    f16* h1new = ws + H1F + ((p ^ 1) * 16 + g) * 131072;
    const float* decp = decb + p * 2048;
    float* decn = decb + (p ^ 1) * 2048;

    WAITF(FDEC, 16 * (t + 1));
    *(f4v*)(decsL + tid * 4) = *(const f4v*)(decp + tid * 4);
    __syncthreads();

    // ---- layer 0: gates = h0old @ W0 (+ dec @ w_ih0), barrier-free GEMM ----
#pragma unroll
    for (int mt = 0; mt < 4; ++mt) {
      const int R0 = wv * 64 + mt * 16;
      h8v a[8]; loadA8(h0old, R0, a);
      f4v ai = fzero(), af = fzero(), ag = fzero(), ao = fzero();
#pragma unroll
      for (int k = 0; k < 8; ++k) {
        ai = mfma16(a[k], BF(0, k), ai);
        af = mfma16(a[k], BF(1, k), af);
        ag = mfma16(a[k], BF(2, k), ag);
        ao = mfma16(a[k], BF(3, k), ao);
      }
#pragma unroll
      for (int j = 0; j < 4; ++j) {
        const int row = R0 + 4 * lg + j;
        f4v d4 = *(const f4v*)(decsL + row * 4);
        const float d0 = d4[0], d1 = d4[1], d2 = d4[2];
        float gi = ai[j] + b0r[0] + d0 * wihr[0][0] + d1 * wihr[0][1] + d2 * wihr[0][2];
        float gf = af[j] + b0r[1] + d0 * wihr[1][0] + d1 * wihr[1][1] + d2 * wihr[1][2];
        float gg = ag[j] + b0r[2] + d0 * wihr[2][0] + d1 * wihr[2][1] + d2 * wihr[2][2];
        float go = ao[j] + b0r[3] + d0 * wihr[3][0] + d1 * wihr[3][1] + d2 * wihr[3][2];
        float cn = sigm(gf) * c0v[mt][j] + sigm(gi) * tanhfast(gg);
        c0v[mt][j] = cn;
        h0new[m * 8192 + row * 16 + lr] = (f16)(sigm(go) * tanhfast(cn));
      }
    }
    RELF(FH0); WAITF(FH0, 16 * (t + 1));

    // ---- layer 1: gates = h0new @ W1i + h1old @ W1h ----
#pragma unroll
    for (int mt = 0; mt < 4; ++mt) {
      const int R0 = wv * 64 + mt * 16;
      f4v ai = fzero(), af = fzero(), ag = fzero(), ao = fzero();
      {
        h8v a[8]; loadA8(h0new, R0, a);
#pragma unroll
        for (int k = 0; k < 8; ++k) {
          ai = mfma16(a[k], BF(4, k), ai);
          af = mfma16(a[k], BF(5, k), af);
          ag = mfma16(a[k], BF(6, k), ag);
          ao = mfma16(a[k], BF(7, k), ao);
        }
      }
      {
        h8v a[8]; loadA8(h1old, R0, a);
#pragma unroll
        for (int k = 0; k < 8; ++k) {
          ai = mfma16(a[k], BF(8,  k), ai);
          af = mfma16(a[k], BF(9,  k), af);
          ag = mfma16(a[k], BF(10, k), ag);
          ao = mfma16(a[k], BF(11, k), ao);
        }
      }
#pragma unroll
      for (int j = 0; j < 4; ++j) {
        const int row = R0 + 4 * lg + j;
        float gi = ai[j] + b1r[0];
        float gf = af[j] + b1r[1];
        float gg = ag[j] + b1r[2];
        float go = ao[j] + b1r[3];
        float cn = sigm(gf) * c1v[mt][j] + sigm(gi) * tanhfast(gg);
        c1v[mt][j] = cn;
        h1new[m * 8192 + row * 16 + lr] = (f16)(sigm(go) * tanhfast(cn));
      }
    }
    RELF(FH1); WAITF(FH1, 16 * (t + 1));

    // ---- head: o1 = relu(h1new @ ow1^T); pair (m, m+8) splits rows ----
    {
      const int Rh = ((m >> 3) << 8) + wv * 32;
#pragma unroll
      for (int mt = 0; mt < 2; ++mt) {
        const int R0 = Rh + mt * 16;
        h8v a[8]; loadA8(h1new, R0, a);
        f4v acc = fzero();
#pragma unroll
        for (int k = 0; k < 8; ++k) acc = mfma16(a[k], BF(12, k), acc);
#pragma unroll
        for (int j = 0; j < 4; ++j)
          o1g[(m & 7) * 8192 + (R0 + 4 * lg + j) * 16 + lr] =
              (f16)fmaxf(acc[j] + ob1r, 0.0f);
      }
    }
    RELF(FO1); WAITF(FO1, 16 * (t + 1));

    // ---- final: out = relu-o1 @ out_w2^T + b2 for member's 32 rows; feed dec ----
    {
      const int r32 = tid >> 4, t8 = (tid & 15) >> 1, hf = tid & 1;
      *(h8v*)(o1s + r32 * 136 + t8 * 16 + hf * 8) =
          *(const h8v*)(o1g + t8 * 8192 + (m * 32 + r32) * 16 + hf * 8);
    }
    __syncthreads();
    {
      const int r = tid >> 4, jj = tid & 15;
      float a0 = 0.f, a1 = 0.f, a2 = 0.f;
#pragma unroll
      for (int kk = 0; kk < 8; ++kk) {
        const int k = jj * 8 + kk;
        const float ov = (float)o1s[r * 136 + k];
        a0 += ov * w2s[k];
        a1 += ov * w2s[128 + k];
        a2 += ov * w2s[256 + k];
      }
#pragma unroll
      for (int s = 8; s >= 1; s >>= 1) {
        a0 += __shfl_xor(a0, s);
        a1 += __shfl_xor(a1, s);
        a2 += __shfl_xor(a2, s);
      }
      if (jj == 0) {
        a0 += ob2s[0]; a1 += ob2s[1]; a2 += ob2s[2];
        float* op = out + ((size_t)(g * 512 + m * 32 + r) * TT + t) * 3;
        op[0] = a0; op[1] = a1; op[2] = a2;
        f4v d; d[0] = a0; d[1] = a1; d[2] = a2; d[3] = 0.f;
        *(f4v*)(decn + (m * 32 + r) * 4) = d;
      }
    }
    RELF(FDEC);
  }
}

extern "C" void kernel_launch(void* const* d_in, const int* in_sizes, int n_in,
                              void* d_out, int out_size, void* d_ws, size_t ws_size,
                              hipStream_t stream) {
  (void)in_sizes; (void)n_in; (void)out_size; (void)ws_size;
  f16* wk = (f16*)d_ws;
  int* flags = (int*)((char*)d_ws + (size_t)FLGF * 2);
  conv_w<<<(FRAG_TOTAL + 255) / 256, 256, 0, stream>>>(
      (const float*)d_in[12], (const float*)d_in[15],
      (const float*)d_in[16], (const float*)d_in[19],
      (const float*)d_in[3],  (const float*)d_in[5],
      (const float*)d_in[7],  (const float*)d_in[9],
      wk, flags);
  traj_kernel<<<NWG, NTHR, 0, stream>>>(
      (const float*)d_in[0],
      (const float*)d_in[1],  (const float*)d_in[2],
      (const float*)d_in[4],  (const float*)d_in[6],
      (const float*)d_in[8],  (const float*)d_in[10],
      (const float*)d_in[11],
      (const float*)d_in[13], (const float*)d_in[14],
      (const float*)d_in[17], (const float*)d_in[18],
      (const float*)d_in[20], (const float*)d_in[21],
      (const float*)d_in[22], (const float*)d_in[23],
      wk, flags, (float*)d_out);
}